// Round 5
// baseline (371.915 us; speedup 1.0000x reference)
//
#include <hip/hip_runtime.h>
#include <hip/hip_bf16.h>

// TaylorMap, symmetric-packed quadratic, uniform-9 pair stream (bf16).
// R17: full restructure of the A-fill onto the global_load_lds DMA path.
//   - Wave split changes from K-halves (g) to BATCH-COLUMN halves (ch):
//     wave (t,ch) computes cols 32ch..32ch+31 over the FULL K range
//     (pairs 0..63 + linear as uniform "pair 64"). K-merge (sc_lds,
//     34.8 KB) disappears -> LDS pays for a depth-3 staging ring:
//     ring[3][4 tiles][9 slices][64 lanes] = 108 KB. Total 160,256 B.
//   - SIMD co-residents are (t,ch0),(t,ch1) (SIMD = w&3): both consume the
//     same staged tile slices; each DMAs its half (ch0: slices 0-4, ch1: 5-8).
//   - Barrier-certified pipeline (T3/T4, m97/m201 pattern), continuous pair
//     counter P = 65*step + p, slot = P%3 (65 % 3 = 2 -> slots rotate
//     continuously across steps; o1 is never reset):
//       top of P: issue GLL(P+2) ; s_waitcnt vmcnt(5|4) (own P+1 done,
//       P+2 stays in flight -- NEVER drains) ; lgkm-only s_barrier
//       (certifies stage P+1 globally) ; consume P from regs with in-place
//       abuf[s] <- ds_read(stage P+1) reloads inside the MFMA chain
//       (R12's proven reload idiom, source moved from global to LDS).
//   - Ring slot safety: GLL(P+2) -> slot(P-1); any laggard wave is at most
//     one barrier behind (in pair P-1), whose reads target slot(P) only;
//     barrier_lgkm's lgkmcnt(0) guarantees its P-2 reads drained. Safe.
// Evidence: direct global->VGPR fill saturates ~31 B/cyc/CU (R12..R15 all
// null at 254 us); DMA path measured ~50 B/cyc/CU (m97). Floor here:
// max(MFMA 581, DMA 36KB@50=737, LDS-read 72KB@85-128) cyc/pair-step
// -> ~160-205 us predicted.

#define DSTATE 128
#define BATCH  16384
#define NSTEPS 7
#define BT     64
#define NSL    585          // slices per d-tile: 65 "pairs" x 9 (incl linear+pad)

typedef __attribute__((ext_vector_type(8)))  short  short8;   // 8 bf16 = 4 VGPRs
typedef __attribute__((ext_vector_type(16))) float  f32x16;   // MFMA 32x32 C/D

__device__ __forceinline__ unsigned short f2bf(float f){
    unsigned int u = __float_as_uint(f);
    u += 0x7fff + ((u >> 16) & 1);          // RNE
    return (unsigned short)(u >> 16);
}

// lgkmcnt-only workgroup barrier: drains LDS ops, NOT the vmem queue.
__device__ __forceinline__ void barrier_lgkm(){
    asm volatile("s_waitcnt lgkmcnt(0)" ::: "memory");
    __builtin_amdgcn_s_barrier();
}

// global -> LDS DMA, 16 B per lane: dest = lds base + lane*16 (linear).
#define GLL(gp, lp) __builtin_amdgcn_global_load_lds(                           \
        (const __attribute__((address_space(1))) void*)(gp),                    \
        (__attribute__((address_space(3))) void*)(lp), 16, 0, 0)

// Pack symmetric-folded W into bf16 MFMA-A fragments, uniform-9 pair stream.
// (unchanged layout from R12..R16)
__global__ void prep_kernel(const float* __restrict__ W, short8* __restrict__ A){
    int gid = blockIdx.x * 256 + threadIdx.x;
    const int ntotal = 4 * 130 * 8 * 64;
    if (gid >= ntotal) return;
    int lane = gid & 63; int r = gid >> 6;
    int s = r & 7;  r >>= 3;
    int row = r % 130;
    int t   = r / 130;
    int d  = t * 32 + (lane & 31);
    int kb = (lane >> 5) * 8;
    int dst;
    bool zero = false;
    if (row < 64){
        int sl = row >> 4;
        if (s < sl) return;
        dst = t * NSL + 9 * row + (s - sl);
    } else if (row < 128){
        int p  = 127 - row;
        int sl = row >> 4;
        if (s < sl) return;
        int ca = 8 - (p >> 4);
        dst = t * NSL + 9 * p + ca + (s - sl);
    } else if (row == 128){
        dst = t * NSL + 576 + s;               // linear (W1) row
    } else {
        if (s) return;                         // zero pad slice
        dst = t * NSL + 584;
        zero = true;
    }
    union { short8 v; unsigned short u[8]; } fr;
#pragma unroll
    for (int e = 0; e < 8; ++e){
        int j = s * 16 + kb + e;
        float v;
        if (zero) v = 0.0f;
        else if (row < 128){
            if      (j < row)  v = 0.0f;
            else if (j == row) v = W[(129 + 128 * row + j) * 128 + d];
            else               v = W[(129 + 128 * row + j) * 128 + d]
                                 + W[(129 + 128 * j + row) * 128 + d];
        } else {
            v = W[(1 + j) * 128 + d];
        }
        fr.u[e] = f2bf(v);
    }
    A[(size_t)dst * 64 + lane] = fr.v;
}

__global__ __launch_bounds__(512)
void taylor_kernel(const float* __restrict__ X, const float* __restrict__ W,
                   const float* __restrict__ tini, const float* __restrict__ lini,
                   const short8* __restrict__ A, float* __restrict__ out)
{
    __shared__ float  x_lds[DSTATE * BT];      // fp32 master state [d][b], 32 KB
    __shared__ float  w0_lds[DSTATE];          // 0.5 KB
    __shared__ short8 bpack[2 * 8 * 64];       // B frags, 2 col-groups x 8, 16 KB
    __shared__ short8 ring[3][4][9][64];       // A staging ring, 108 KB

    const int tid  = threadIdx.x;
    const int lane = tid & 63;
    const int w    = tid >> 6;
    const int t    = w & 3;                    // d-tile (SIMD = w&3 -> co-residents share t)
    const int ch   = w >> 2;                   // batch-column half (cols 32ch..32ch+31)
    const int ln   = lane & 31;
    const int hi   = lane >> 5;
    const int b0   = blockIdx.x * BT;
    const int c0   = 32 * ch;

    // per-lane global src base for this wave's tile
    const char* const Atl = (const char*)A + ((size_t)t * NSL * 64 + lane) * 16;

    // ch0 DMAs slices 0..4 of each staged pair, ch1 slices 5..8
#define ISSUE(SRCP, SL)                                                         \
    {                                                                           \
        const char* gb_ = Atl + (size_t)(9 * (SRCP)) * 1024;                    \
        if (ch == 0){                                                           \
            _Pragma("unroll")                                                   \
            for (int s2 = 0; s2 < 5; ++s2)                                      \
                GLL(gb_ + s2 * 1024, &ring[SL][t][s2][0]);                      \
        } else {                                                                \
            _Pragma("unroll")                                                   \
            for (int s2 = 5; s2 < 9; ++s2)                                      \
                GLL(gb_ + s2 * 1024, &ring[SL][t][s2][0]);                      \
        }                                                                       \
    }
    // own outstanding after ISSUE = 2 batches; wait leaves the newest batch
#define WAITV()                                                                 \
    { if (ch == 0) asm volatile("s_waitcnt vmcnt(5)" ::: "memory");             \
      else         asm volatile("s_waitcnt vmcnt(4)" ::: "memory"); }

    // ---- prologue: pre-issue stages for pairs 0 and 1 (slots 0,1) ----
    ISSUE(0, 0)
    ISSUE(1, 1)

    // ---- init x0 = [X | t_init | l_init] ----
#pragma unroll
    for (int it = 0; it < 16; ++it){
        int entry = tid + it * 512;            // entry = b*128 + d
        int b = entry >> 7, d = entry & 127;
        float v;
        if      (d < 120) v = X[(b0 + b) * 120 + d];
        else if (d < 124) v = tini[d - 120];
        else              v = lini[d - 124];
        x_lds[d * BT + b] = v;
    }
    if (tid < DSTATE) w0_lds[tid] = W[tid];

    WAITV();                                   // own GLL(0) done (over-waits X; once)

    const f32x16 zero16 = {};
    short8 abuf[9];
    short8 bfrag[8];
    f32x16 acc;
    int o1 = 1;                                // slot of pair P+1 (continuous; never reset)

#pragma unroll 1
    for (int step = 0; step < NSTEPS; ++step){
        barrier_lgkm();                        // (A) x_lds stable; step0: stage0 certified

        const bool active = (step < NSTEPS - 1) || (t == 3);

        if (step == 0){                        // first stage -> registers
#pragma unroll
            for (int s = 0; s < 9; ++s) abuf[s] = ring[0][t][s][lane];
        }

        // ---- build bpack (1024 frags, 2 per thread) ----
#pragma unroll
        for (int f0 = 0; f0 < 2; ++f0){
            int f  = tid + f0 * 512;
            int gg = f >> 9, s = (f >> 6) & 7, l = f & 63;
            int c  = gg * 32 + (l & 31);
            int jb = 16 * s + 8 * (l >> 5);
            union { short8 v; unsigned short u[8]; } fr;
#pragma unroll
            for (int e = 0; e < 8; ++e)
                fr.u[e] = f2bf(x_lds[(jb + e) * BT + c]);
            bpack[f] = fr.v;
        }

        // ---- acc init: x_old + W0 (this wave's cols; no K-split -> no merge) ----
        if (active){
#pragma unroll
            for (int r = 0; r < 16; ++r){
                int d = 32 * t + (r & 3) + 8 * (r >> 2) + 4 * hi;
                acc[r] = x_lds[d * BT + c0 + ln] + w0_lds[d];
            }
        }

        barrier_lgkm();                        // (B) bpack visible

        if (active){
#pragma unroll
            for (int s = 0; s < 8; ++s)
                bfrag[s] = bpack[ch * 512 + s * 64 + lane];
        }

        // ---- pair loop: p = 0..63 quadratic + p = 64 linear ----
        // Y: slices 0..7-BK (j-block BK+s), Z: slices 8-BK..8 (j-block 7-BK+s)
#define PBLOCK(BK)                                                              \
        _Pragma("unroll 2")                                                     \
        for (int q = 0; q < 16; ++q){                                           \
            const int p = 16 * (BK) + q;                                        \
            int o2 = (o1 == 2) ? 0 : o1 + 1;                                    \
            if (active){                                                        \
                int srcp = (p == 63) ? 0 : p + 2;   /* wrap into next step */   \
                ISSUE(srcp, o2)                                                 \
                WAITV()                                                         \
            }                                                                   \
            barrier_lgkm();                    /* stage p+1 globally ready */   \
            if (active){                                                        \
                float s0 = x_lds[p * BT + c0 + ln];                             \
                float s1 = x_lds[(127 - p) * BT + c0 + ln];                     \
                f32x16 Y;                                                       \
                _Pragma("unroll")                                               \
                for (int s = 0; s < 8 - (BK); ++s){                             \
                    Y = __builtin_amdgcn_mfma_f32_32x32x16_bf16(abuf[s], bfrag[(BK) + s], s ? Y : zero16, 0, 0, 0); \
                    abuf[s] = ring[o1][t][s][lane];                             \
                }                                                               \
                acc += s0 * Y;                                                  \
                f32x16 Z;                                                       \
                _Pragma("unroll")                                               \
                for (int s = 0; s < 1 + (BK); ++s){                             \
                    Z = __builtin_amdgcn_mfma_f32_32x32x16_bf16(abuf[8 - (BK) + s], bfrag[7 - (BK) + s], s ? Z : zero16, 0, 0, 0); \
                    abuf[8 - (BK) + s] = ring[o1][t][8 - (BK) + s][lane];       \
                }                                                               \
                acc += s1 * Z;                                                  \
            }                                                                   \
            o1 = o2;                                                            \
        }

        PBLOCK(0) PBLOCK(1) PBLOCK(2) PBLOCK(3)
#undef PBLOCK

        // ---- linear (W1) row = pair 64: C-operand accumulate; reloads pull
        //      next step's pair 0 into abuf ----
        {
            int o2 = (o1 == 2) ? 0 : o1 + 1;
            if (active){
                ISSUE(1, o2)                   // next step's pair 1
                WAITV()
            }
            barrier_lgkm();                    // next-step stage 0 certified
            if (active){
#pragma unroll
                for (int s = 0; s < 8; ++s){
                    acc = __builtin_amdgcn_mfma_f32_32x32x16_bf16(abuf[s], bfrag[s], acc, 0, 0, 0);
                    abuf[s] = ring[o1][t][s][lane];
                }
                abuf[8] = ring[o1][t][8][lane];
            }
            o1 = o2;
        }

        // ---- writeback / output (no merge needed) ----
        if (active){
            if (step < NSTEPS - 1){
#pragma unroll
                for (int r = 0; r < 16; ++r){
                    int d = 32 * t + (r & 3) + 8 * (r >> 2) + 4 * hi;
                    x_lds[d * BT + c0 + ln] = acc[r];
                }
            } else if (hi == 0){
                // out dims 120..123 -> tile 3, regs 12..15 @ hi==0
                *(float4*)(out + (size_t)(b0 + c0 + ln) * 4) =
                    make_float4(acc[12], acc[13], acc[14], acc[15]);
            }
        }
        // next iteration's barrier (A) orders x writes vs bpack reads
    }
#undef ISSUE
#undef WAITV
}

extern "C" void kernel_launch(void* const* d_in, const int* in_sizes, int n_in,
                              void* d_out, int out_size, void* d_ws, size_t ws_size,
                              hipStream_t stream)
{
    const float* X  = (const float*)d_in[0];
    const float* W  = (const float*)d_in[1];
    const float* ti = (const float*)d_in[2];
    const float* li = (const float*)d_in[3];
    float* out      = (float*)d_out;
    short8* A       = (short8*)d_ws;           // 4*585*64*16 B = 2.40 MB

    const int ntotal = 4 * 130 * 8 * 64;
    prep_kernel<<<(ntotal + 255) / 256, 256, 0, stream>>>(W, A);
    taylor_kernel<<<BATCH / BT, 512, 0, stream>>>(X, W, ti, li, A, out);
}